// Round 3
// baseline (2377.454 us; speedup 1.0000x reference)
//
#include <hip/hip_runtime.h>
#include <hip/hip_bf16.h>
#include <math.h>

__device__ __forceinline__ float sigmoidf_(float x) {
    return 1.0f / (1.0f + expf(-x));
}

// ---------------------------------------------------------------------------
// Degree histogram over col (destination) indices. deg must be zeroed first.
// ---------------------------------------------------------------------------
__global__ void k_deg(const int* __restrict__ col, int* __restrict__ deg, int E) {
    int e = blockIdx.x * 256 + threadIdx.x;
    if (e < E) atomicAdd(&deg[col[e]], 1);
}

// dinv[n] = 1/sqrt(deg[n] + 1)   (+1 for the self loop; always > 0)
__global__ void k_dinv(const int* __restrict__ deg, float* __restrict__ dinv, int n) {
    int i = blockIdx.x * 256 + threadIdx.x;
    if (i < n) dinv[i] = 1.0f / sqrtf((float)(deg[i] + 1));
}

// ---------------------------------------------------------------------------
// Fused LSTM step + (h @ W1). One thread per node.
//   gates = x @ W_ih^T + b_ih + b_hh   (f gate dead: c0 = 0)
//   c = sig(i)*tanh(g); h = sig(o)*tanh(c)
//   hw1[n][s] = sum_j h[j] * W1[j*64+s]
// Weight accesses are wave-uniform -> scalar loads.
// All register arrays statically indexed (k/s loops fully unrolled).
// ---------------------------------------------------------------------------
__global__ __launch_bounds__(256) void k_lstm_mm1(
    const float* __restrict__ x, const float* __restrict__ Wih,
    const float* __restrict__ bih, const float* __restrict__ bhh,
    const float* __restrict__ W1, float* __restrict__ hw1, int n)
{
    int node = blockIdx.x * 256 + threadIdx.x;
    if (node >= n) return;

    float xr[64];
    const float4* xp = reinterpret_cast<const float4*>(x + (size_t)node * 64);
#pragma unroll
    for (int q = 0; q < 16; q++) {
        float4 v = xp[q];
        xr[4*q+0] = v.x; xr[4*q+1] = v.y; xr[4*q+2] = v.z; xr[4*q+3] = v.w;
    }

    float acc[64];
#pragma unroll
    for (int s = 0; s < 64; s++) acc[s] = 0.0f;

    for (int j = 0; j < 64; j++) {
        float gi = bih[j]       + bhh[j];
        float gg = bih[128 + j] + bhh[128 + j];
        float go = bih[192 + j] + bhh[192 + j];
        const float* wi = Wih + (size_t)j * 64;
        const float* wg = Wih + (size_t)(128 + j) * 64;
        const float* wo = Wih + (size_t)(192 + j) * 64;
#pragma unroll
        for (int k = 0; k < 64; k++) {
            float xv = xr[k];
            gi = fmaf(xv, wi[k], gi);
            gg = fmaf(xv, wg[k], gg);
            go = fmaf(xv, wo[k], go);
        }
        float c  = sigmoidf_(gi) * tanhf(gg);
        float hj = sigmoidf_(go) * tanhf(c);

        const float* w1r = W1 + (size_t)j * 64;
#pragma unroll
        for (int s = 0; s < 64; s++) acc[s] = fmaf(hj, w1r[s], acc[s]);
    }

    float4* op = reinterpret_cast<float4*>(hw1 + (size_t)node * 64);
#pragma unroll
    for (int q = 0; q < 16; q++)
        op[q] = make_float4(acc[4*q], acc[4*q+1], acc[4*q+2], acc[4*q+3]);
}

// ---------------------------------------------------------------------------
// Edge scatter: F4 = feature-width/4. Thread t -> edge t/F4, float4 group t%F4.
//   acc[col] += hw[row] * dinv[row]*dinv[col]
// ---------------------------------------------------------------------------
template <int F4>
__global__ void k_scatter(const float* __restrict__ hw, const int* __restrict__ row,
                          const int* __restrict__ col, const float* __restrict__ dinv,
                          float* __restrict__ acc, int E)
{
    int t = blockIdx.x * 256 + threadIdx.x;
    int e = t / F4;
    int q = t % F4;
    if (e >= E) return;
    int r = row[e], c = col[e];
    float nrm = dinv[r] * dinv[c];
    const float4 v = *reinterpret_cast<const float4*>(hw + (size_t)r * (F4 * 4) + q * 4);
    float* a = acc + (size_t)c * (F4 * 4) + q * 4;
    atomicAdd(a + 0, v.x * nrm);
    atomicAdd(a + 1, v.y * nrm);
    atomicAdd(a + 2, v.z * nrm);
    atomicAdd(a + 3, v.w * nrm);
}

// ---------------------------------------------------------------------------
// Epilogue 1 (in place on acc1): h1 = relu(acc1 + hw1 * dinv^2 + b1)
// One thread per float4 group: t in [0, n*16)
// ---------------------------------------------------------------------------
__global__ void k_epi1(float* __restrict__ acc1, const float* __restrict__ hw1,
                       const float* __restrict__ dinv, const float* __restrict__ b1, int n)
{
    int t = blockIdx.x * 256 + threadIdx.x;
    if (t >= n * 16) return;
    int node = t >> 4, q = t & 15;
    float sn = dinv[node]; sn = sn * sn;
    float4 a  = reinterpret_cast<const float4*>(acc1)[t];
    float4 hv = reinterpret_cast<const float4*>(hw1)[t];
    float4 b  = reinterpret_cast<const float4*>(b1)[q];
    a.x = fmaxf(fmaf(hv.x, sn, a.x) + b.x, 0.0f);
    a.y = fmaxf(fmaf(hv.y, sn, a.y) + b.y, 0.0f);
    a.z = fmaxf(fmaf(hv.z, sn, a.z) + b.z, 0.0f);
    a.w = fmaxf(fmaf(hv.w, sn, a.w) + b.w, 0.0f);
    reinterpret_cast<float4*>(acc1)[t] = a;
}

// ---------------------------------------------------------------------------
// hw2 = h1 @ W2  ([n,64] x [64,32]). Block = 128 nodes, h1 tile staged in LDS
// (row pad 65 -> conflict-free: bank = (lane + k) % 32, 2 lanes/bank = free).
// ---------------------------------------------------------------------------
__global__ __launch_bounds__(128) void k_mm2(
    const float* __restrict__ h1, const float* __restrict__ W2,
    float* __restrict__ hw2, int n)
{
    __shared__ float tile[128 * 65];
    int base  = blockIdx.x * 128;
    int nrows = n - base; if (nrows > 128) nrows = 128;

    for (int idx = threadIdx.x; idx < nrows * 64; idx += 128) {
        int r = idx >> 6, c = idx & 63;
        tile[r * 65 + c] = h1[(size_t)base * 64 + idx];
    }
    __syncthreads();

    int node = base + threadIdx.x;
    if (node >= n) return;

    const float* hrow = &tile[threadIdx.x * 65];
    float acc[32];
#pragma unroll
    for (int s = 0; s < 32; s++) acc[s] = 0.0f;

    for (int k = 0; k < 64; k++) {
        float hk = hrow[k];
        const float* w = W2 + (size_t)k * 32;
#pragma unroll
        for (int s = 0; s < 32; s++) acc[s] = fmaf(hk, w[s], acc[s]);
    }

    float4* op = reinterpret_cast<float4*>(hw2 + (size_t)node * 32);
#pragma unroll
    for (int q = 0; q < 8; q++)
        op[q] = make_float4(acc[4*q], acc[4*q+1], acc[4*q+2], acc[4*q+3]);
}

// ---------------------------------------------------------------------------
// Epilogue 2 (in place on acc2): z = acc2 + hw2 * dinv^2 + b2   (no relu)
// t in [0, n*8) float4 groups
// ---------------------------------------------------------------------------
__global__ void k_epi2(float* __restrict__ acc2, const float* __restrict__ hw2,
                       const float* __restrict__ dinv, const float* __restrict__ b2, int n)
{
    int t = blockIdx.x * 256 + threadIdx.x;
    if (t >= n * 8) return;
    int node = t >> 3, q = t & 7;
    float sn = dinv[node]; sn = sn * sn;
    float4 a  = reinterpret_cast<const float4*>(acc2)[t];
    float4 hv = reinterpret_cast<const float4*>(hw2)[t];
    float4 b  = reinterpret_cast<const float4*>(b2)[q];
    a.x = fmaf(hv.x, sn, a.x) + b.x;
    a.y = fmaf(hv.y, sn, a.y) + b.y;
    a.z = fmaf(hv.z, sn, a.z) + b.z;
    a.w = fmaf(hv.w, sn, a.w) + b.w;
    reinterpret_cast<float4*>(acc2)[t] = a;
}

// ---------------------------------------------------------------------------
// out[e] = dot(z[src[e]], z[dst[e]]) over 32 features
// ---------------------------------------------------------------------------
__global__ void k_dot(const float* __restrict__ z, const int* __restrict__ src,
                      const int* __restrict__ dst, float* __restrict__ out, int EL)
{
    int e = blockIdx.x * 256 + threadIdx.x;
    if (e >= EL) return;
    const float4* a = reinterpret_cast<const float4*>(z + (size_t)src[e] * 32);
    const float4* b = reinterpret_cast<const float4*>(z + (size_t)dst[e] * 32);
    float s = 0.0f;
#pragma unroll
    for (int q = 0; q < 8; q++) {
        float4 av = a[q], bv = b[q];
        s = fmaf(av.x, bv.x, s);
        s = fmaf(av.y, bv.y, s);
        s = fmaf(av.z, bv.z, s);
        s = fmaf(av.w, bv.w, s);
    }
    out[e] = s;
}

extern "C" void kernel_launch(void* const* d_in, const int* in_sizes, int n_in,
                              void* d_out, int out_size, void* d_ws, size_t ws_size,
                              hipStream_t stream)
{
    const float* x   = (const float*)d_in[0];
    const int*   ei  = (const int*)d_in[1];
    const int*   eli = (const int*)d_in[2];
    const float* Wih = (const float*)d_in[3];
    // d_in[4] = W_hh: mathematically dead (h0 = c0 = 0)
    const float* bih = (const float*)d_in[5];
    const float* bhh = (const float*)d_in[6];
    const float* W1  = (const float*)d_in[7];
    const float* b1  = (const float*)d_in[8];
    const float* W2  = (const float*)d_in[9];
    const float* b2  = (const float*)d_in[10];

    int n  = in_sizes[0] / 64;
    int E  = in_sizes[1] / 2;
    int EL = in_sizes[2] / 2;

    const int* row  = ei;          // source
    const int* col  = ei + E;      // destination
    const int* lsrc = eli;
    const int* ldst = eli + EL;
    float* out = (float*)d_out;

    // Workspace layout (floats): bufA [n*64] hw1 | bufB [n*64] acc1/acc2/z |
    //                            bufC [n*32] hw2 | deg [n] int | dinv [n]
    float* bufA = (float*)d_ws;
    float* bufB = bufA + (size_t)n * 64;
    float* bufC = bufB + (size_t)n * 64;
    int*   deg  = (int*)(bufC + (size_t)n * 32);
    float* dinv = (float*)(deg + n);

    dim3 blk(256);

    // degrees + dinv
    hipMemsetAsync(deg, 0, (size_t)n * sizeof(int), stream);
    k_deg<<<dim3((E + 255) / 256), blk, 0, stream>>>(col, deg, E);
    k_dinv<<<dim3((n + 255) / 256), blk, 0, stream>>>(deg, dinv, n);

    // LSTM + first matmul
    k_lstm_mm1<<<dim3((n + 255) / 256), blk, 0, stream>>>(x, Wih, bih, bhh, W1, bufA, n);

    // GCN1 scatter
    hipMemsetAsync(bufB, 0, (size_t)n * 64 * sizeof(float), stream);
    {
        int T = E * 16;
        k_scatter<16><<<dim3((T + 255) / 256), blk, 0, stream>>>(bufA, row, col, dinv, bufB, E);
    }
    k_epi1<<<dim3((n * 16 + 255) / 256), blk, 0, stream>>>(bufB, bufA, dinv, b1, n);

    // second matmul
    k_mm2<<<dim3((n + 127) / 128), dim3(128), 0, stream>>>(bufB, W2, bufC, n);

    // GCN2 scatter (reuse bufB's first n*32 as acc2)
    hipMemsetAsync(bufB, 0, (size_t)n * 32 * sizeof(float), stream);
    {
        int T = E * 8;
        k_scatter<8><<<dim3((T + 255) / 256), blk, 0, stream>>>(bufC, row, col, dinv, bufB, E);
    }
    k_epi2<<<dim3((n * 8 + 255) / 256), blk, 0, stream>>>(bufB, bufC, dinv, b2, n);

    // edge dot products
    k_dot<<<dim3((EL + 255) / 256), blk, 0, stream>>>(bufB, lsrc, ldst, out, EL);
}

// Round 4
// 2374.776 us; speedup vs baseline: 1.0011x; 1.0011x over previous
//
#include <hip/hip_runtime.h>
#include <hip/hip_bf16.h>
#include <math.h>

__device__ __forceinline__ float sigmoidf_(float x) {
    return 1.0f / (1.0f + expf(-x));
}

// ---------------------------------------------------------------------------
// Degree histogram over col (destination) indices. deg must be zeroed first.
// ---------------------------------------------------------------------------
__global__ void k_deg(const int* __restrict__ col, int* __restrict__ deg, int E) {
    int e = blockIdx.x * 256 + threadIdx.x;
    if (e < E) atomicAdd(&deg[col[e]], 1);
}

// dinv[n] = 1/sqrt(deg[n] + 1)   (+1 for the self loop; always > 0)
__global__ void k_dinv(const int* __restrict__ deg, float* __restrict__ dinv, int n) {
    int i = blockIdx.x * 256 + threadIdx.x;
    if (i < n) dinv[i] = 1.0f / sqrtf((float)(deg[i] + 1));
}

// ---------------------------------------------------------------------------
// Fused LSTM step + (h @ W1). One thread per node.
//   gates = x @ W_ih^T + b_ih + b_hh   (f gate dead: c0 = 0)
//   c = sig(i)*tanh(g); h = sig(o)*tanh(c)
//   hw1[n][s] = sum_j h[j] * W1[j*64+s]
// Weight accesses are wave-uniform -> scalar loads.
// All register arrays statically indexed (k/s loops fully unrolled).
// ---------------------------------------------------------------------------
__global__ __launch_bounds__(256) void k_lstm_mm1(
    const float* __restrict__ x, const float* __restrict__ Wih,
    const float* __restrict__ bih, const float* __restrict__ bhh,
    const float* __restrict__ W1, float* __restrict__ hw1, int n)
{
    int node = blockIdx.x * 256 + threadIdx.x;
    if (node >= n) return;

    float xr[64];
    const float4* xp = reinterpret_cast<const float4*>(x + (size_t)node * 64);
#pragma unroll
    for (int q = 0; q < 16; q++) {
        float4 v = xp[q];
        xr[4*q+0] = v.x; xr[4*q+1] = v.y; xr[4*q+2] = v.z; xr[4*q+3] = v.w;
    }

    float acc[64];
#pragma unroll
    for (int s = 0; s < 64; s++) acc[s] = 0.0f;

    for (int j = 0; j < 64; j++) {
        float gi = bih[j]       + bhh[j];
        float gg = bih[128 + j] + bhh[128 + j];
        float go = bih[192 + j] + bhh[192 + j];
        const float* wi = Wih + (size_t)j * 64;
        const float* wg = Wih + (size_t)(128 + j) * 64;
        const float* wo = Wih + (size_t)(192 + j) * 64;
#pragma unroll
        for (int k = 0; k < 64; k++) {
            float xv = xr[k];
            gi = fmaf(xv, wi[k], gi);
            gg = fmaf(xv, wg[k], gg);
            go = fmaf(xv, wo[k], go);
        }
        float c  = sigmoidf_(gi) * tanhf(gg);
        float hj = sigmoidf_(go) * tanhf(c);

        const float* w1r = W1 + (size_t)j * 64;
#pragma unroll
        for (int s = 0; s < 64; s++) acc[s] = fmaf(hj, w1r[s], acc[s]);
    }

    float4* op = reinterpret_cast<float4*>(hw1 + (size_t)node * 64);
#pragma unroll
    for (int q = 0; q < 16; q++)
        op[q] = make_float4(acc[4*q], acc[4*q+1], acc[4*q+2], acc[4*q+3]);
}

// ---------------------------------------------------------------------------
// Edge scatter: F4 = feature-width/4. Thread t -> edge t/F4, float4 group t%F4.
//   acc[col] += hw[row] * dinv[row]*dinv[col]
// ---------------------------------------------------------------------------
template <int F4>
__global__ void k_scatter(const float* __restrict__ hw, const int* __restrict__ row,
                          const int* __restrict__ col, const float* __restrict__ dinv,
                          float* __restrict__ acc, int E)
{
    int t = blockIdx.x * 256 + threadIdx.x;
    int e = t / F4;
    int q = t % F4;
    if (e >= E) return;
    int r = row[e], c = col[e];
    float nrm = dinv[r] * dinv[c];
    const float4 v = *reinterpret_cast<const float4*>(hw + (size_t)r * (F4 * 4) + q * 4);
    float* a = acc + (size_t)c * (F4 * 4) + q * 4;
    atomicAdd(a + 0, v.x * nrm);
    atomicAdd(a + 1, v.y * nrm);
    atomicAdd(a + 2, v.z * nrm);
    atomicAdd(a + 3, v.w * nrm);
}

// ---------------------------------------------------------------------------
// Epilogue 1 (in place on acc1): h1 = relu(acc1 + hw1 * dinv^2 + b1)
// One thread per float4 group: t in [0, n*16)
// ---------------------------------------------------------------------------
__global__ void k_epi1(float* __restrict__ acc1, const float* __restrict__ hw1,
                       const float* __restrict__ dinv, const float* __restrict__ b1, int n)
{
    int t = blockIdx.x * 256 + threadIdx.x;
    if (t >= n * 16) return;
    int node = t >> 4, q = t & 15;
    float sn = dinv[node]; sn = sn * sn;
    float4 a  = reinterpret_cast<const float4*>(acc1)[t];
    float4 hv = reinterpret_cast<const float4*>(hw1)[t];
    float4 b  = reinterpret_cast<const float4*>(b1)[q];
    a.x = fmaxf(fmaf(hv.x, sn, a.x) + b.x, 0.0f);
    a.y = fmaxf(fmaf(hv.y, sn, a.y) + b.y, 0.0f);
    a.z = fmaxf(fmaf(hv.z, sn, a.z) + b.z, 0.0f);
    a.w = fmaxf(fmaf(hv.w, sn, a.w) + b.w, 0.0f);
    reinterpret_cast<float4*>(acc1)[t] = a;
}

// ---------------------------------------------------------------------------
// hw2 = h1 @ W2  ([n,64] x [64,32]). Block = 128 nodes, h1 tile staged in LDS
// (row pad 65 -> conflict-free: bank = (lane + k) % 32, 2 lanes/bank = free).
// ---------------------------------------------------------------------------
__global__ __launch_bounds__(128) void k_mm2(
    const float* __restrict__ h1, const float* __restrict__ W2,
    float* __restrict__ hw2, int n)
{
    __shared__ float tile[128 * 65];
    int base  = blockIdx.x * 128;
    int nrows = n - base; if (nrows > 128) nrows = 128;

    for (int idx = threadIdx.x; idx < nrows * 64; idx += 128) {
        int r = idx >> 6, c = idx & 63;
        tile[r * 65 + c] = h1[(size_t)base * 64 + idx];
    }
    __syncthreads();

    int node = base + threadIdx.x;
    if (node >= n) return;

    const float* hrow = &tile[threadIdx.x * 65];
    float acc[32];
#pragma unroll
    for (int s = 0; s < 32; s++) acc[s] = 0.0f;

    for (int k = 0; k < 64; k++) {
        float hk = hrow[k];
        const float* w = W2 + (size_t)k * 32;
#pragma unroll
        for (int s = 0; s < 32; s++) acc[s] = fmaf(hk, w[s], acc[s]);
    }

    float4* op = reinterpret_cast<float4*>(hw2 + (size_t)node * 32);
#pragma unroll
    for (int q = 0; q < 8; q++)
        op[q] = make_float4(acc[4*q], acc[4*q+1], acc[4*q+2], acc[4*q+3]);
}

// ---------------------------------------------------------------------------
// Epilogue 2 (in place on acc2): z = acc2 + hw2 * dinv^2 + b2   (no relu)
// t in [0, n*8) float4 groups
// ---------------------------------------------------------------------------
__global__ void k_epi2(float* __restrict__ acc2, const float* __restrict__ hw2,
                       const float* __restrict__ dinv, const float* __restrict__ b2, int n)
{
    int t = blockIdx.x * 256 + threadIdx.x;
    if (t >= n * 8) return;
    int node = t >> 3, q = t & 7;
    float sn = dinv[node]; sn = sn * sn;
    float4 a  = reinterpret_cast<const float4*>(acc2)[t];
    float4 hv = reinterpret_cast<const float4*>(hw2)[t];
    float4 b  = reinterpret_cast<const float4*>(b2)[q];
    a.x = fmaf(hv.x, sn, a.x) + b.x;
    a.y = fmaf(hv.y, sn, a.y) + b.y;
    a.z = fmaf(hv.z, sn, a.z) + b.z;
    a.w = fmaf(hv.w, sn, a.w) + b.w;
    reinterpret_cast<float4*>(acc2)[t] = a;
}

// ---------------------------------------------------------------------------
// out[e] = dot(z[src[e]], z[dst[e]]) over 32 features
// ---------------------------------------------------------------------------
__global__ void k_dot(const float* __restrict__ z, const int* __restrict__ src,
                      const int* __restrict__ dst, float* __restrict__ out, int EL)
{
    int e = blockIdx.x * 256 + threadIdx.x;
    if (e >= EL) return;
    const float4* a = reinterpret_cast<const float4*>(z + (size_t)src[e] * 32);
    const float4* b = reinterpret_cast<const float4*>(z + (size_t)dst[e] * 32);
    float s = 0.0f;
#pragma unroll
    for (int q = 0; q < 8; q++) {
        float4 av = a[q], bv = b[q];
        s = fmaf(av.x, bv.x, s);
        s = fmaf(av.y, bv.y, s);
        s = fmaf(av.z, bv.z, s);
        s = fmaf(av.w, bv.w, s);
    }
    out[e] = s;
}

extern "C" void kernel_launch(void* const* d_in, const int* in_sizes, int n_in,
                              void* d_out, int out_size, void* d_ws, size_t ws_size,
                              hipStream_t stream)
{
    const float* x   = (const float*)d_in[0];
    const int*   ei  = (const int*)d_in[1];
    const int*   eli = (const int*)d_in[2];
    const float* Wih = (const float*)d_in[3];
    // d_in[4] = W_hh: mathematically dead (h0 = c0 = 0)
    const float* bih = (const float*)d_in[5];
    const float* bhh = (const float*)d_in[6];
    const float* W1  = (const float*)d_in[7];
    const float* b1  = (const float*)d_in[8];
    const float* W2  = (const float*)d_in[9];
    const float* b2  = (const float*)d_in[10];

    int n  = in_sizes[0] / 64;
    int E  = in_sizes[1] / 2;
    int EL = in_sizes[2] / 2;

    const int* row  = ei;          // source
    const int* col  = ei + E;      // destination
    const int* lsrc = eli;
    const int* ldst = eli + EL;
    float* out = (float*)d_out;

    // Workspace layout (floats): bufA [n*64] hw1 | bufB [n*64] acc1/acc2/z |
    //                            bufC [n*32] hw2 | deg [n] int | dinv [n]
    float* bufA = (float*)d_ws;
    float* bufB = bufA + (size_t)n * 64;
    float* bufC = bufB + (size_t)n * 64;
    int*   deg  = (int*)(bufC + (size_t)n * 32);
    float* dinv = (float*)(deg + n);

    dim3 blk(256);

    // degrees + dinv
    hipMemsetAsync(deg, 0, (size_t)n * sizeof(int), stream);
    k_deg<<<dim3((E + 255) / 256), blk, 0, stream>>>(col, deg, E);
    k_dinv<<<dim3((n + 255) / 256), blk, 0, stream>>>(deg, dinv, n);

    // LSTM + first matmul
    k_lstm_mm1<<<dim3((n + 255) / 256), blk, 0, stream>>>(x, Wih, bih, bhh, W1, bufA, n);

    // GCN1 scatter
    hipMemsetAsync(bufB, 0, (size_t)n * 64 * sizeof(float), stream);
    {
        int T = E * 16;
        k_scatter<16><<<dim3((T + 255) / 256), blk, 0, stream>>>(bufA, row, col, dinv, bufB, E);
    }
    k_epi1<<<dim3((n * 16 + 255) / 256), blk, 0, stream>>>(bufB, bufA, dinv, b1, n);

    // second matmul
    k_mm2<<<dim3((n + 127) / 128), dim3(128), 0, stream>>>(bufB, W2, bufC, n);

    // GCN2 scatter (reuse bufB's first n*32 as acc2)
    hipMemsetAsync(bufB, 0, (size_t)n * 32 * sizeof(float), stream);
    {
        int T = E * 8;
        k_scatter<8><<<dim3((T + 255) / 256), blk, 0, stream>>>(bufC, row, col, dinv, bufB, E);
    }
    k_epi2<<<dim3((n * 8 + 255) / 256), blk, 0, stream>>>(bufB, bufC, dinv, b2, n);

    // edge dot products
    k_dot<<<dim3((EL + 255) / 256), blk, 0, stream>>>(bufB, lsrc, ldst, out, EL);
}

// Round 5
// 653.738 us; speedup vs baseline: 3.6367x; 3.6326x over previous
//
#include <hip/hip_runtime.h>
#include <hip/hip_bf16.h>
#include <math.h>

__device__ __forceinline__ float sigmoidf_(float x) {
    return 1.0f / (1.0f + expf(-x));
}

// ---------------------------------------------------------------------------
// Degree histogram over col (destination) indices. deg must be zeroed first.
// ---------------------------------------------------------------------------
__global__ void k_deg(const int* __restrict__ col, int* __restrict__ deg, int E) {
    int e = blockIdx.x * 256 + threadIdx.x;
    if (e < E) atomicAdd(&deg[col[e]], 1);
}

// dinv[n] = 1/sqrt(deg[n] + 1)   (+1 for the self loop; always > 0)
__global__ void k_dinv(const int* __restrict__ deg, float* __restrict__ dinv, int n) {
    int i = blockIdx.x * 256 + threadIdx.x;
    if (i < n) dinv[i] = 1.0f / sqrtf((float)(deg[i] + 1));
}

// ---------------------------------------------------------------------------
// Hierarchical exclusive scan of deg -> off (CSR row offsets).
// scan1: per-block (256) exclusive scan + block sums
// scan2: single block (1024) exclusive scan of block sums (nb <= 1024)
// scan3: add block offset; init cursor; write off[n] = E
// ---------------------------------------------------------------------------
__global__ __launch_bounds__(256) void k_scan1(const int* __restrict__ deg,
        int* __restrict__ off, int* __restrict__ bsum, int n) {
    __shared__ int tmp[256];
    int tid = threadIdx.x;
    int i = blockIdx.x * 256 + tid;
    int v = (i < n) ? deg[i] : 0;
    tmp[tid] = v;
    __syncthreads();
#pragma unroll
    for (int s = 1; s < 256; s <<= 1) {
        int t = (tid >= s) ? tmp[tid - s] : 0;
        __syncthreads();
        tmp[tid] += t;
        __syncthreads();
    }
    if (i < n) off[i] = tmp[tid] - v;             // block-local exclusive
    if (tid == 255) bsum[blockIdx.x] = tmp[255];  // block total
}

__global__ __launch_bounds__(1024) void k_scan2(const int* __restrict__ bsum,
        int* __restrict__ bscan, int nb) {
    __shared__ int tmp[1024];
    int tid = threadIdx.x;
    int v = (tid < nb) ? bsum[tid] : 0;
    tmp[tid] = v;
    __syncthreads();
#pragma unroll
    for (int s = 1; s < 1024; s <<= 1) {
        int t = (tid >= s) ? tmp[tid - s] : 0;
        __syncthreads();
        tmp[tid] += t;
        __syncthreads();
    }
    if (tid < nb) bscan[tid] = tmp[tid] - v;
}

__global__ __launch_bounds__(256) void k_scan3(int* __restrict__ off,
        const int* __restrict__ bscan, const int* __restrict__ deg,
        int* __restrict__ cur, int n) {
    int i = blockIdx.x * 256 + threadIdx.x;
    if (i >= n) return;
    int o = off[i] + bscan[blockIdx.x];
    off[i] = o;
    cur[i] = o;
    if (i == n - 1) off[n] = o + deg[i];
}

// Fill CSR neighbor lists (grouped by destination, stores source index).
__global__ void k_fill(const int* __restrict__ row, const int* __restrict__ col,
                       int* __restrict__ cur, int* __restrict__ nbr, int E) {
    int e = blockIdx.x * 256 + threadIdx.x;
    if (e < E) {
        int c = col[e];
        int p = atomicAdd(&cur[c], 1);
        nbr[p] = row[e];
    }
}

// ---------------------------------------------------------------------------
// Fused LSTM step + (h @ W1). One thread per node.
//   gates = x @ W_ih^T + b_ih + b_hh   (f gate dead: c0 = 0)
//   c = sig(i)*tanh(g); h = sig(o)*tanh(c)
//   hw1[n][s] = sum_j h[j] * W1[j*64+s]
// ---------------------------------------------------------------------------
__global__ __launch_bounds__(256) void k_lstm_mm1(
    const float* __restrict__ x, const float* __restrict__ Wih,
    const float* __restrict__ bih, const float* __restrict__ bhh,
    const float* __restrict__ W1, float* __restrict__ hw1, int n)
{
    int node = blockIdx.x * 256 + threadIdx.x;
    if (node >= n) return;

    float xr[64];
    const float4* xp = reinterpret_cast<const float4*>(x + (size_t)node * 64);
#pragma unroll
    for (int q = 0; q < 16; q++) {
        float4 v = xp[q];
        xr[4*q+0] = v.x; xr[4*q+1] = v.y; xr[4*q+2] = v.z; xr[4*q+3] = v.w;
    }

    float acc[64];
#pragma unroll
    for (int s = 0; s < 64; s++) acc[s] = 0.0f;

    for (int j = 0; j < 64; j++) {
        float gi = bih[j]       + bhh[j];
        float gg = bih[128 + j] + bhh[128 + j];
        float go = bih[192 + j] + bhh[192 + j];
        const float* wi = Wih + (size_t)j * 64;
        const float* wg = Wih + (size_t)(128 + j) * 64;
        const float* wo = Wih + (size_t)(192 + j) * 64;
#pragma unroll
        for (int k = 0; k < 64; k++) {
            float xv = xr[k];
            gi = fmaf(xv, wi[k], gi);
            gg = fmaf(xv, wg[k], gg);
            go = fmaf(xv, wo[k], go);
        }
        float c  = sigmoidf_(gi) * tanhf(gg);
        float hj = sigmoidf_(go) * tanhf(c);

        const float* w1r = W1 + (size_t)j * 64;
#pragma unroll
        for (int s = 0; s < 64; s++) acc[s] = fmaf(hj, w1r[s], acc[s]);
    }

    float4* op = reinterpret_cast<float4*>(hw1 + (size_t)node * 64);
#pragma unroll
    for (int q = 0; q < 16; q++)
        op[q] = make_float4(acc[4*q], acc[4*q+1], acc[4*q+2], acc[4*q+3]);
}

// ---------------------------------------------------------------------------
// Pull aggregation, F=64. One wave per node, lane = feature.
// Fused epilogue 1: h1 = relu(agg*dc + hw1[node]*dc^2 + b1)
//   (edge norm dinv[r]*dinv[c] factored: dc * sum(hw[r]*dinv[r]))
// Per neighbor: one coalesced 256B row read; no atomics.
// ---------------------------------------------------------------------------
__global__ __launch_bounds__(256) void k_pull64(
    const float* __restrict__ hw, const int* __restrict__ off,
    const int* __restrict__ nbr, const float* __restrict__ dinv,
    const float* __restrict__ b1, float* __restrict__ h1, int n)
{
    int node = (blockIdx.x * 256 + threadIdx.x) >> 6;
    int lane = threadIdx.x & 63;
    if (node >= n) return;
    int s = off[node], e = off[node + 1];
    float a0 = 0.0f, a1 = 0.0f;
    int j = s;
    for (; j + 2 <= e; j += 2) {           // 2 neighbors in flight
        int r0 = nbr[j], r1 = nbr[j + 1];
        float w0 = dinv[r0], w1 = dinv[r1];
        a0 = fmaf(hw[(size_t)r0 * 64 + lane], w0, a0);
        a1 = fmaf(hw[(size_t)r1 * 64 + lane], w1, a1);
    }
    if (j < e) {
        int r0 = nbr[j];
        a0 = fmaf(hw[(size_t)r0 * 64 + lane], dinv[r0], a0);
    }
    float dc   = dinv[node];
    float self = hw[(size_t)node * 64 + lane];
    float v = (a0 + a1) * dc + self * dc * dc + b1[lane];
    h1[(size_t)node * 64 + lane] = fmaxf(v, 0.0f);
}

// ---------------------------------------------------------------------------
// Pull aggregation, F=32. One wave per node; lanes 0-31 take even neighbors,
// lanes 32-63 odd neighbors (feat = lane&31); halves combined via shfl_xor 32.
// Fused epilogue 2: z = agg*dc + hw2[node]*dc^2 + b2  (no relu)
// ---------------------------------------------------------------------------
__global__ __launch_bounds__(256) void k_pull32(
    const float* __restrict__ hw, const int* __restrict__ off,
    const int* __restrict__ nbr, const float* __restrict__ dinv,
    const float* __restrict__ b2, float* __restrict__ z, int n)
{
    int node = (blockIdx.x * 256 + threadIdx.x) >> 6;
    int lane = threadIdx.x & 63;
    int feat = lane & 31;
    int half = lane >> 5;
    if (node >= n) return;
    int s = off[node], e = off[node + 1];
    float acc = 0.0f;
    for (int j = s + half; j < e; j += 2) {
        int r = nbr[j];
        acc = fmaf(hw[(size_t)r * 32 + feat], dinv[r], acc);
    }
    acc += __shfl_xor(acc, 32, 64);        // combine even/odd halves
    float dc = dinv[node];
    float v = acc * dc + hw[(size_t)node * 32 + feat] * dc * dc + b2[feat];
    if (half == 0) z[(size_t)node * 32 + feat] = v;
}

// ---------------------------------------------------------------------------
// hw2 = h1 @ W2  ([n,64] x [64,32]). Block = 128 nodes, h1 tile in LDS (pad 65).
// ---------------------------------------------------------------------------
__global__ __launch_bounds__(128) void k_mm2(
    const float* __restrict__ h1, const float* __restrict__ W2,
    float* __restrict__ hw2, int n)
{
    __shared__ float tile[128 * 65];
    int base  = blockIdx.x * 128;
    int nrows = n - base; if (nrows > 128) nrows = 128;

    for (int idx = threadIdx.x; idx < nrows * 64; idx += 128) {
        int r = idx >> 6, c = idx & 63;
        tile[r * 65 + c] = h1[(size_t)base * 64 + idx];
    }
    __syncthreads();

    int node = base + threadIdx.x;
    if (node >= n) return;

    const float* hrow = &tile[threadIdx.x * 65];
    float acc[32];
#pragma unroll
    for (int s = 0; s < 32; s++) acc[s] = 0.0f;

    for (int k = 0; k < 64; k++) {
        float hk = hrow[k];
        const float* w = W2 + (size_t)k * 32;
#pragma unroll
        for (int s = 0; s < 32; s++) acc[s] = fmaf(hk, w[s], acc[s]);
    }

    float4* op = reinterpret_cast<float4*>(hw2 + (size_t)node * 32);
#pragma unroll
    for (int q = 0; q < 8; q++)
        op[q] = make_float4(acc[4*q], acc[4*q+1], acc[4*q+2], acc[4*q+3]);
}

// ---------------------------------------------------------------------------
// out[e] = dot(z[src[e]], z[dst[e]]) over 32 features
// ---------------------------------------------------------------------------
__global__ void k_dot(const float* __restrict__ z, const int* __restrict__ src,
                      const int* __restrict__ dst, float* __restrict__ out, int EL)
{
    int e = blockIdx.x * 256 + threadIdx.x;
    if (e >= EL) return;
    const float4* a = reinterpret_cast<const float4*>(z + (size_t)src[e] * 32);
    const float4* b = reinterpret_cast<const float4*>(z + (size_t)dst[e] * 32);
    float s = 0.0f;
#pragma unroll
    for (int q = 0; q < 8; q++) {
        float4 av = a[q], bv = b[q];
        s = fmaf(av.x, bv.x, s);
        s = fmaf(av.y, bv.y, s);
        s = fmaf(av.z, bv.z, s);
        s = fmaf(av.w, bv.w, s);
    }
    out[e] = s;
}

extern "C" void kernel_launch(void* const* d_in, const int* in_sizes, int n_in,
                              void* d_out, int out_size, void* d_ws, size_t ws_size,
                              hipStream_t stream)
{
    const float* x   = (const float*)d_in[0];
    const int*   ei  = (const int*)d_in[1];
    const int*   eli = (const int*)d_in[2];
    const float* Wih = (const float*)d_in[3];
    // d_in[4] = W_hh: mathematically dead (h0 = c0 = 0)
    const float* bih = (const float*)d_in[5];
    const float* bhh = (const float*)d_in[6];
    const float* W1  = (const float*)d_in[7];
    const float* b1  = (const float*)d_in[8];
    const float* W2  = (const float*)d_in[9];
    const float* b2  = (const float*)d_in[10];

    int n  = in_sizes[0] / 64;
    int E  = in_sizes[1] / 2;
    int EL = in_sizes[2] / 2;

    const int* row  = ei;          // source
    const int* col  = ei + E;      // destination
    const int* lsrc = eli;
    const int* ldst = eli + EL;
    float* out = (float*)d_out;

    // Workspace layout (4B units), liveness-aliased:
    //   bufA [n*64]: hw1 (lstm..pull64), then hw2 in first n*32 (mm2..pull32)
    //   bufB [n*64]: h1  (pull64..mm2), then z   in first n*32 (pull32..dot)
    //   dinv [n] | off [n+1] | deg [n] | cur [n] | bsum [1024] | bscan [1024]
    //   nbr [E]
    // Total ~= 59.2 MB (< the 64.8 MB proven available in round 0).
    float* bufA  = (float*)d_ws;
    float* bufB  = bufA + (size_t)n * 64;
    float* dinv  = bufB + (size_t)n * 64;
    int*   off   = (int*)(dinv + n);
    int*   deg   = off + (n + 1);
    int*   cur   = deg + n;
    int*   bsum  = cur + n;
    int*   bscan = bsum + 1024;
    int*   nbr   = bscan + 1024;

    int nb = (n + 255) / 256;      // 391 for n=100000; k_scan2 handles nb<=1024
    dim3 blk(256);

    // --- CSR build (deterministic counting sort by destination) ---
    hipMemsetAsync(deg, 0, (size_t)n * sizeof(int), stream);
    k_deg  <<<dim3((E + 255) / 256), blk, 0, stream>>>(col, deg, E);
    k_dinv <<<dim3(nb), blk, 0, stream>>>(deg, dinv, n);
    k_scan1<<<dim3(nb), blk, 0, stream>>>(deg, off, bsum, n);
    k_scan2<<<dim3(1), dim3(1024), 0, stream>>>(bsum, bscan, nb);
    k_scan3<<<dim3(nb), blk, 0, stream>>>(off, bscan, deg, cur, n);
    k_fill <<<dim3((E + 255) / 256), blk, 0, stream>>>(row, col, cur, nbr, E);

    // --- LSTM + first matmul: hw1 -> bufA ---
    k_lstm_mm1<<<dim3(nb), blk, 0, stream>>>(x, Wih, bih, bhh, W1, bufA, n);

    // --- GCN1: pull + fused epilogue (relu) : h1 -> bufB ---
    {
        int blocks = (int)(((size_t)n * 64 + 255) / 256);
        k_pull64<<<dim3(blocks), blk, 0, stream>>>(bufA, off, nbr, dinv, b1, bufB, n);
    }

    // --- second matmul: hw2 -> bufA (hw1 dead) ---
    k_mm2<<<dim3((n + 127) / 128), dim3(128), 0, stream>>>(bufB, W2, bufA, n);

    // --- GCN2: pull + fused epilogue : z -> bufB (h1 dead) ---
    {
        int blocks = (int)(((size_t)n * 64 + 255) / 256);
        k_pull32<<<dim3(blocks), blk, 0, stream>>>(bufA, off, nbr, dinv, b2, bufB, n);
    }

    // --- edge dot products ---
    k_dot<<<dim3((EL + 255) / 256), blk, 0, stream>>>(bufB, lsrc, ldst, out, EL);
}